// Round 1
// 1128.891 us; speedup vs baseline: 1.0568x; 1.0568x over previous
//
#include <hip/hip_runtime.h>
#include <hip/hip_bf16.h>
#include <math.h>

// ---------------------------------------------------------------------------
// TSRL fused forward, MFMA edition (round 5: occupancy).
// Round-4 counters: MfmaUtil=9.4, VALUBusy=14.3, HBM=2.3%, Occupancy=23.4%,
// LDS=62976B -> 2 blocks/CU. Latency-bound: nothing is saturated.
// This round: LDS 62.7KB -> 38.4KB => 4 blocks/CU (16 waves/CU):
//  * Activation buffers aliased: A = h0 -> h_b0(raw);  B = gelu chain.
//    In-place overwrite guarded by read-complete barrier; residual h0 goes
//    through registers. Clamped halo rows only ever feed discarded D rows
//    (matmul is row-local), so stale data in rows 0/43 stays harmless.
//  * TB1 trimmed to its 36 live rows (p-4 indexing).
//  * Pass-2: Rr written after an explicit barrier (acc stays in VGPRs),
//    aliased at offset 0; zb halved to per-mt 16-row chunks (wave-private,
//    DS ops are in-order within a wave -> dense-loop barriers removed).
//  * __launch_bounds__(256,4) caps VGPR at 128 for 4 blocks/CU.
//  * Passes interleaved (bid%3) to mix heavy pass-2 blocks across the grid.
// ---------------------------------------------------------------------------

#define BB    128
#define TSEQ  512
#define NTILE 16
#define DIN   12
#define C0    64
#define C1    320
#define TT    32
#define PP    44
#define HALO  6
#define R64P  72      // bf16 elems/row (144B = 36 dw == 4 mod 32)
#define R320P 328     // bf16 elems/row (656B = 164 dw == 4 mod 32)

#define S1 ((size_t)BB * TSEQ * C1)
#define S2 ((size_t)BB * TSEQ * DIN)

typedef __attribute__((ext_vector_type(8))) __bf16 bf16x8;
typedef __attribute__((ext_vector_type(4))) float f32x4;
#define MFMA16(a, b, c) __builtin_amdgcn_mfma_f32_16x16x32_bf16(a, b, c, 0, 0, 0)

// workspace (bf16 elem offsets): transposed bf16 weights Bt[n][k]
#define O01 0         // c01wT [64][192]
#define O02 12288     // c02wT [64][192]
#define O11 24576     // c11wT [320][192]
#define O12 86016     // c12wT [320][1024]  (k<960: conv taps; k>=960: c1_p 1x1)
#define OD  413696    // dwT   [1280][320]
#define OP  823296    // pwT   [16][1280]   (rows 12..15 zero)
#define NWS 843776    // total bf16 elems (1.69 MB) -- requires ws_size >= this*2

// LDS byte offsets (38448 total => 4 blocks/CU)
#define LA  0         // A: h0 raw, later h_b0 raw (T1)   [44][R64P]  6336
#define LB  6336      // B: gelu(h0) -> gelu(t0) -> gelu(h_b0)        6336
#define LC  12672     // TB1: gelu(c1_1 out), rows p-4    [36][R320P] 23616
#define LXI 36288     // x_interp fp32 [32][12]    1536
#define LGM 37824     // fc_w@fcr_w    [12][12]    576
#define LF2 38400     // fused bias    [12]        48
#define LSZ 38448
// pass-2 aliases (dead regions only):
#define LRR 0         // enc-out [32][R320P] bf16 = 20992 (A,B,C all dead)
#define LZB 20992     // per-wave per-mt z chunk [16][R64P] bf16 = 2304 each

__device__ __forceinline__ float bf2f(const __hip_bfloat16 v) { return __bfloat162float(v); }
__device__ __forceinline__ __hip_bfloat16 f2bf(float f)       { return __float2bfloat16(f); }
__device__ __forceinline__ float geluf(float x) {
    return 0.5f * x * (1.0f + erff(x * 0.7071067811865475f));
}
__device__ __forceinline__ bf16x8 ldb8(const void* p) { return *(const bf16x8*)p; }

// ---- weight prep: fp32 -> bf16 transposed, every launch (ws re-poisoned) ----
extern "C" __global__ void __launch_bounds__(256) prep_w(
    const float* __restrict__ c01w, const float* __restrict__ c02w,
    const float* __restrict__ c11w, const float* __restrict__ c12w,
    const float* __restrict__ c1pw, const float* __restrict__ dw,
    const float* __restrict__ pw,   __hip_bfloat16* __restrict__ ws)
{
    for (size_t i = (size_t)blockIdx.x * 256 + threadIdx.x; i < NWS;
         i += (size_t)gridDim.x * 256) {
        float v;
        if (i < O02)      { int q = (int)i;        int n = q / 192, r = q % 192;
                            v = c01w[(n * 64 + (r & 63)) * 3 + (r >> 6)]; }
        else if (i < O11) { int q = (int)(i - O02); int n = q / 192, r = q % 192;
                            v = c02w[(n * 64 + (r & 63)) * 3 + (r >> 6)]; }
        else if (i < O12) { int q = (int)(i - O11); int n = q / 192, r = q % 192;
                            v = c11w[(n * 64 + (r & 63)) * 3 + (r >> 6)]; }
        else if (i < OD)  { int q = (int)(i - O12); int n = q >> 10, k = q & 1023;
                            v = (k < 960) ? c12w[(n * 320 + (k % 320)) * 3 + (k / 320)]
                                          : c1pw[n * 64 + (k - 960)]; }
        else if (i < OP)  { int q = (int)(i - OD);  int h = q / 320, c = q % 320;
                            v = dw[c * 1280 + h]; }
        else              { int q = (int)(i - OP);  int j = q / 1280, h = q % 1280;
                            v = (j < 12) ? pw[h * 12 + j] : 0.f; }
        ws[i] = f2bf(v);
    }
}

extern "C" __global__ void __launch_bounds__(256, 4) fused_main(
    const float* __restrict__ x1,  const float* __restrict__ X1,
    const float* __restrict__ X2,
    const float* __restrict__ w_in, const float* __restrict__ b_in,
    const float* __restrict__ c01b, const float* __restrict__ c02b,
    const float* __restrict__ c1pb, const float* __restrict__ c11b,
    const float* __restrict__ c12b,
    const float* __restrict__ db,   const float* __restrict__ pb,
    const float* __restrict__ fcw,  const float* __restrict__ fcb,
    const float* __restrict__ fcrw, const float* __restrict__ fcrb,
    const __hip_bfloat16* __restrict__ ws,
    float* __restrict__ out)
{
    __shared__ __align__(16) unsigned char smem[LSZ];
    __hip_bfloat16* A  = (__hip_bfloat16*)(smem + LA);   // h0 -> T1
    __hip_bfloat16* Bf = (__hip_bfloat16*)(smem + LB);   // G0 -> T0 -> GH
    __hip_bfloat16* C  = (__hip_bfloat16*)(smem + LC);   // TB1 (rows p-4)
    float* XI = (float*)(smem + LXI);
    float* Gm = (float*)(smem + LGM);
    float* F2 = (float*)(smem + LF2);
    __hip_bfloat16* Rr = (__hip_bfloat16*)(smem + LRR);

    const int tid  = threadIdx.x;
    const int wv   = tid >> 6;
    const int lane = tid & 63;
    const int lm   = lane & 15;        // MFMA: A row / B col / D col
    const int lq   = lane >> 4;        // MFMA: k-octet / D row-quad
    const int bid  = blockIdx.x;
    const int pass = bid % 3;          // interleave heavy pass-2 blocks
    const int rem  = bid / 3;
    const int b    = rem >> 4;
    const int t0   = (rem & (NTILE - 1)) * TT;
    const float* xin = (pass == 0) ? X1 : (pass == 1) ? X2 : x1;

    const f32x4 Z4 = {0.f, 0.f, 0.f, 0.f};

    // ---- pass-2 prep: Gm = fc_w@fcr_w, F2 = fc_b@fcr_w+fcr_b, XI = pb ------
    if (pass == 2) {
        for (int o = tid; o < 144; o += 256) {
            int j = o / 12, j2 = o - j * 12;
            float s = 0.f;
            for (int c = 0; c < C1; c++) s += fcw[j * C1 + c] * fcrw[c * 12 + j2];
            Gm[o] = s;
        }
        if (tid < 12) {
            float s = fcrb[tid];
            for (int c = 0; c < C1; c++) s += fcb[c] * fcrw[c * 12 + tid];
            F2[tid] = s;
        }
        for (int o = tid; o < TT * 12; o += 256) XI[o] = pb[o % 12];  // ih_proj_b
    }

    // ---- L0: x@w_in + b_in, rows [0,44) ------------------------------------
    for (int o = tid; o < PP * C0; o += 256) {
        int p = o >> 6, c = o & 63;
        int t = t0 + p - HALO;
        float acc = 0.f;
        if (t >= 0 && t < TSEQ) {
            acc = b_in[c];
            const float4* xr4 = (const float4*)(xin + ((size_t)b * TSEQ + t) * DIN);
            float4 v0 = xr4[0], v1 = xr4[1], v2 = xr4[2];
            const float xv[12] = {v0.x, v0.y, v0.z, v0.w, v1.x, v1.y,
                                  v1.z, v1.w, v2.x, v2.y, v2.z, v2.w};
            #pragma unroll
            for (int i = 0; i < DIN; i++) acc += xv[i] * w_in[i * C0 + c];
        }
        A [p * R64P + c] = f2bf(acc);
        Bf[p * R64P + c] = f2bf(geluf(acc));
    }
    __syncthreads();

    // ---- L1: conv0_1 64->64 k3 d1 on gelu(h0)=Bf, rows [1,43) --------------
    {
        const int oc = wv * 16 + lm;
        f32x4 acc[3] = {Z4, Z4, Z4};
        #pragma unroll
        for (int ks = 0; ks < 6; ks++) {
            int tap = ks >> 1, ci = ((ks & 1) << 5) + (lq << 3);
            bf16x8 bf = ldb8(ws + O01 + oc * 192 + ks * 32 + (lq << 3));
            #pragma unroll
            for (int mt = 0; mt < 3; mt++) {
                int p = 1 + mt * 16 + lm + tap - 1; p = p > 43 ? 43 : p;
                acc[mt] = MFMA16(ldb8(Bf + p * R64P + ci), bf, acc[mt]);
            }
        }
        __syncthreads();   // all waves done reading G0 before overwrite
        float bias = c01b[oc];
        #pragma unroll
        for (int mt = 0; mt < 3; mt++)
            #pragma unroll
            for (int r = 0; r < 4; r++) {
                int m = mt * 16 + lq * 4 + r;
                if (m < 42) {
                    int p = 1 + m, t = t0 + p - HALO;
                    Bf[p * R64P + oc] =
                        f2bf((t >= 0 && t < TSEQ) ? geluf(acc[mt][r] + bias) : 0.f);
                }
            }
    }
    __syncthreads();

    // ---- L2: conv0_2 64->64 k3 d1 on T0=Bf + residual h0=A, rows [2,42) ----
    {
        const int oc = wv * 16 + lm;
        f32x4 acc[3] = {Z4, Z4, Z4};
        #pragma unroll
        for (int ks = 0; ks < 6; ks++) {
            int tap = ks >> 1, ci = ((ks & 1) << 5) + (lq << 3);
            bf16x8 bf = ldb8(ws + O02 + oc * 192 + ks * 32 + (lq << 3));
            #pragma unroll
            for (int mt = 0; mt < 3; mt++) {
                int p = 2 + mt * 16 + lm + tap - 1; p = p > 43 ? 43 : p;
                acc[mt] = MFMA16(ldb8(Bf + p * R64P + ci), bf, acc[mt]);
            }
        }
        // snapshot residual h0 before A is overwritten
        float resv[3][4];
        #pragma unroll
        for (int mt = 0; mt < 3; mt++)
            #pragma unroll
            for (int r = 0; r < 4; r++) {
                int m = mt * 16 + lq * 4 + r;
                resv[mt][r] = (m < 40) ? bf2f(A[(2 + m) * R64P + oc]) : 0.f;
            }
        __syncthreads();   // all waves done reading T0 (Bf) and h0 (A)
        float bias = c02b[oc];
        #pragma unroll
        for (int mt = 0; mt < 3; mt++)
            #pragma unroll
            for (int r = 0; r < 4; r++) {
                int m = mt * 16 + lq * 4 + r;
                if (m < 40) {
                    int p = 2 + m, t = t0 + p - HALO;
                    bool v = (t >= 0 && t < TSEQ);
                    float hb = acc[mt][r] + bias + resv[mt][r];
                    A [p * R64P + oc] = f2bf(v ? hb : 0.f);          // T1 raw
                    Bf[p * R64P + oc] = f2bf(v ? geluf(hb) : 0.f);   // GH
                }
            }
    }
    __syncthreads();

    // ---- L3: c1_1 64->320 k3 d2 on gelu(h_b0)=Bf, rows [4,40) --------------
    {
        f32x4 acc[3][5];
        #pragma unroll
        for (int mt = 0; mt < 3; mt++)
            #pragma unroll
            for (int nt = 0; nt < 5; nt++) acc[mt][nt] = Z4;
        #pragma unroll
        for (int ks = 0; ks < 6; ks++) {
            int tap = ks >> 1, ci = ((ks & 1) << 5) + (lq << 3);
            bf16x8 a[3];
            #pragma unroll
            for (int mt = 0; mt < 3; mt++) {
                int p = 4 + mt * 16 + lm + 2 * (tap - 1); p = p > 43 ? 43 : p;
                a[mt] = ldb8(Bf + p * R64P + ci);
            }
            #pragma unroll
            for (int nt = 0; nt < 5; nt++) {
                int oc = wv * 80 + nt * 16 + lm;
                bf16x8 bf = ldb8(ws + O11 + oc * 192 + ks * 32 + (lq << 3));
                #pragma unroll
                for (int mt = 0; mt < 3; mt++)
                    acc[mt][nt] = MFMA16(a[mt], bf, acc[mt][nt]);
            }
        }
        #pragma unroll
        for (int nt = 0; nt < 5; nt++) {
            int oc = wv * 80 + nt * 16 + lm;
            float bias = c11b[oc];
            #pragma unroll
            for (int mt = 0; mt < 3; mt++)
                #pragma unroll
                for (int r = 0; r < 4; r++) {
                    int m = mt * 16 + lq * 4 + r;
                    if (m < 36) {
                        int t = t0 + 4 + m - HALO;
                        C[m * R320P + oc] =
                            f2bf((t >= 0 && t < TSEQ) ? geluf(acc[mt][nt][r] + bias) : 0.f);
                    }
                }
        }
    }
    __syncthreads();

    // ---- L4: c1_2 320->320 k3 d2 (K=960) + c1_p 1x1 on raw h_b0 (K=64) -----
    {
        f32x4 acc[2][5];
        #pragma unroll
        for (int mt = 0; mt < 2; mt++)
            #pragma unroll
            for (int nt = 0; nt < 5; nt++) acc[mt][nt] = Z4;
        for (int ks = 0; ks < 32; ks++) {
            bf16x8 a[2];
            if (ks < 30) {
                int tap = (ks >= 20) ? 2 : (ks >= 10 ? 1 : 0);
                int ci = (ks - tap * 10) * 32 + (lq << 3);
                #pragma unroll
                for (int mt = 0; mt < 2; mt++) {
                    int row = 2 + mt * 16 + lm + 2 * (tap - 1);   // p-4
                    a[mt] = ldb8(C + row * R320P + ci);
                }
            } else {
                int ci = ((ks - 30) << 5) + (lq << 3);
                #pragma unroll
                for (int mt = 0; mt < 2; mt++)
                    a[mt] = ldb8(A + (6 + mt * 16 + lm) * R64P + ci);
            }
            #pragma unroll
            for (int nt = 0; nt < 5; nt++) {
                int oc = wv * 80 + nt * 16 + lm;
                bf16x8 bf = ldb8(ws + O12 + oc * 1024 + ks * 32 + (lq << 3));
                #pragma unroll
                for (int mt = 0; mt < 2; mt++)
                    acc[mt][nt] = MFMA16(a[mt], bf, acc[mt][nt]);
            }
        }
        if (pass < 2) {
            #pragma unroll
            for (int nt = 0; nt < 5; nt++) {
                int oc = wv * 80 + nt * 16 + lm;
                float bias = c12b[oc] + c1pb[oc];
                const size_t obase = (pass == 1) ? S1 : (size_t)0;
                #pragma unroll
                for (int mt = 0; mt < 2; mt++)
                    #pragma unroll
                    for (int r = 0; r < 4; r++) {
                        int m = mt * 16 + lq * 4 + r;
                        out[obase + ((size_t)b * TSEQ + t0 + m) * C1 + oc] =
                            acc[mt][nt][r] + bias;
                    }
            }
        } else {
            __syncthreads();   // all waves done reading C,A -> safe to alias
            #pragma unroll
            for (int nt = 0; nt < 5; nt++) {
                int oc = wv * 80 + nt * 16 + lm;
                float bias = c12b[oc] + c1pb[oc];
                #pragma unroll
                for (int mt = 0; mt < 2; mt++)
                    #pragma unroll
                    for (int r = 0; r < 4; r++) {
                        int m = mt * 16 + lq * 4 + r;
                        Rr[m * R320P + oc] = f2bf(acc[mt][nt][r] + bias);
                    }
            }
            __syncthreads();   // Rr complete (cross-wave K in dense stage)
        }
    }

    // ---- pass-2: dense 320->1280, relu, @pw (MFMA), @Gm, outputs -----------
    if (pass == 2) {
        // zb: wave-private 16-row chunk; DS ops are in-order within a wave,
        // so no barriers are needed in this loop.
        __hip_bfloat16* zb = (__hip_bfloat16*)(smem + LZB) + wv * (16 * R64P);
        f32x4 xacc[2] = {Z4, Z4};
        for (int cn = 0; cn < 5; cn++) {
            int h0 = wv * 320 + cn * 64;
            f32x4 dacc[2][4];
            #pragma unroll
            for (int mt = 0; mt < 2; mt++)
                #pragma unroll
                for (int nt = 0; nt < 4; nt++) dacc[mt][nt] = Z4;
            for (int ks = 0; ks < 10; ks++) {
                int ci = ks * 32 + (lq << 3);
                bf16x8 a[2];
                #pragma unroll
                for (int mt = 0; mt < 2; mt++)
                    a[mt] = ldb8(Rr + (mt * 16 + lm) * R320P + ci);
                #pragma unroll
                for (int nt = 0; nt < 4; nt++) {
                    int h = h0 + nt * 16 + lm;
                    bf16x8 bf = ldb8(ws + OD + h * 320 + ci);
                    #pragma unroll
                    for (int mt = 0; mt < 2; mt++)
                        dacc[mt][nt] = MFMA16(a[mt], bf, dacc[mt][nt]);
                }
            }
            #pragma unroll
            for (int mt = 0; mt < 2; mt++) {
                #pragma unroll
                for (int nt = 0; nt < 4; nt++) {
                    int h = h0 + nt * 16 + lm;
                    float bb = db[h];
                    #pragma unroll
                    for (int r = 0; r < 4; r++)
                        zb[(lq * 4 + r) * R64P + nt * 16 + lm] =
                            f2bf(fmaxf(dacc[mt][nt][r] + bb, 0.f));
                }
                #pragma unroll
                for (int k2 = 0; k2 < 2; k2++) {
                    int hl = k2 * 32 + (lq << 3);
                    bf16x8 bf = ldb8(ws + OP + lm * 1280 + h0 + hl);
                    xacc[mt] = MFMA16(ldb8(zb + lm * R64P + hl), bf, xacc[mt]);
                }
            }
        }
        if (lm < 12) {
            #pragma unroll
            for (int mt = 0; mt < 2; mt++)
                #pragma unroll
                for (int r = 0; r < 4; r++)
                    atomicAdd(&XI[(mt * 16 + lq * 4 + r) * 12 + lm], xacc[mt][r]);
        }
        __syncthreads();
        for (int o = tid; o < TT * 12; o += 256) {
            int p = o / 12, j2 = o - p * 12;
            float val = F2[j2];
            #pragma unroll
            for (int j = 0; j < 12; j++) val += XI[p * 12 + j] * Gm[j * 12 + j2];
            size_t idx = ((size_t)b * TSEQ + t0 + p) * DIN + j2;
            out[2 * S1 + idx]      = val;   // outputs1
            out[2 * S1 + S2 + idx] = val;   // outputs2 (ref uses y_t1 for both)
        }
    }
}

// ---- masks + passthrough: m1, m2, x1, x2 -----------------------------------
extern "C" __global__ void __launch_bounds__(256) tail_kernel(
    const float* __restrict__ x1, const float* __restrict__ x2,
    float* __restrict__ out)
{
    size_t i = (size_t)blockIdx.x * 256 + threadIdx.x;
    if (i >= S2) return;
    float a = x1[i], c = x2[i];
    const size_t base = 2 * S1 + 2 * S2;
    out[base + i]          = (a != 0.f) ? 1.f : 0.f;
    out[base + S2 + i]     = (c != 0.f) ? 1.f : 0.f;
    out[base + 2 * S2 + i] = a;
    out[base + 3 * S2 + i] = c;
}

extern "C" void kernel_launch(void* const* d_in, const int* in_sizes, int n_in,
                              void* d_out, int out_size, void* d_ws, size_t ws_size,
                              hipStream_t stream)
{
    (void)in_sizes; (void)n_in; (void)ws_size; (void)out_size;
    const float* x1   = (const float*)d_in[0];
    const float* x2   = (const float*)d_in[1];
    const float* X1   = (const float*)d_in[2];
    const float* X2   = (const float*)d_in[3];
    const float* w_in = (const float*)d_in[5];
    const float* b_in = (const float*)d_in[6];
    const float* c01w = (const float*)d_in[7];
    const float* c01b = (const float*)d_in[8];
    const float* c02w = (const float*)d_in[9];
    const float* c02b = (const float*)d_in[10];
    const float* c1pw = (const float*)d_in[11];
    const float* c1pb = (const float*)d_in[12];
    const float* c11w = (const float*)d_in[13];
    const float* c11b = (const float*)d_in[14];
    const float* c12w = (const float*)d_in[15];
    const float* c12b = (const float*)d_in[16];
    const float* dwp  = (const float*)d_in[17];
    const float* dbp  = (const float*)d_in[18];
    const float* pwp  = (const float*)d_in[19];
    const float* pbp  = (const float*)d_in[20];
    const float* fcw  = (const float*)d_in[21];
    const float* fcb  = (const float*)d_in[22];
    const float* fcrw = (const float*)d_in[29];
    const float* fcrb = (const float*)d_in[30];
    float* out = (float*)d_out;
    __hip_bfloat16* ws = (__hip_bfloat16*)d_ws;

    prep_w<<<824, 256, 0, stream>>>(c01w, c02w, c11w, c12w, c1pw, dwp, pwp, ws);

    fused_main<<<3 * BB * NTILE, 256, 0, stream>>>(
        x1, X1, X2, w_in, b_in, c01b, c02b, c1pb, c11b, c12b,
        dbp, pbp, fcw, fcb, fcrw, fcrb, ws, out);

    tail_kernel<<<(int)((S2 + 255) / 256), 256, 0, stream>>>(x1, x2, out);
}

// Round 2
// 825.951 us; speedup vs baseline: 1.4444x; 1.3668x over previous
//
#include <hip/hip_runtime.h>
#include <hip/hip_bf16.h>
#include <math.h>

// ---------------------------------------------------------------------------
// TSRL fused forward, MFMA edition (round 6: latency pipelining + TT=64).
// Round-5 post-mortem: occupancy 23->40% bought only 5%. MfmaUtil 9.9,
// VALUBusy 14, HBM 3.7 => per-wave exposed L2 latency in rolled load->MFMA
// loops, lockstepped by barriers. This round:
//  * Explicit even/odd register double-buffer prefetch of B-fragments
//    (global, L2-hot) and A-fragments (LDS) in L3 / L4 / dense loops:
//    issue ks+1 loads, then run ks's MFMA cluster (~40 MFMA of cover).
//  * TT 32->64 (PP=76): halves B-frag loads + L2 weight traffic per output
//    (mt=4..5 reuse), halo waste 37%->19%. LDS refit: C overlays dead Bf
//    after L3 (extra barrier); 59.2KB -> 2 blocks/CU (occupancy ~25% --
//    round-5 showed occupancy isn't the binding constraint).
//  * Gm = fc_w@fcr_w / F2 precompute moved into prep_w (block 0).
// Row masking at TT=64 re-derived: garbage rows from clamped/stale halo
// reads always land at D rows >= mask bound (L1 m<74, L2 m<72, L3 m<68,
// L4 exact 64). Verified per-tap below each stage.
// ---------------------------------------------------------------------------

#define BB    128
#define TSEQ  512
#define NTILE 8
#define DIN   12
#define C0    64
#define C1    320
#define TT    64
#define PP    76
#define HALO  6
#define R64P  72      // bf16 elems/row (144B = 36 dw == 4 mod 32)
#define R320P 328     // bf16 elems/row (656B = 164 dw == 4 mod 32)

#define S1 ((size_t)BB * TSEQ * C1)
#define S2 ((size_t)BB * TSEQ * DIN)

typedef __attribute__((ext_vector_type(8))) __bf16 bf16x8;
typedef __attribute__((ext_vector_type(4))) float f32x4;
#define MFMA16(a, b, c) __builtin_amdgcn_mfma_f32_16x16x32_bf16(a, b, c, 0, 0, 0)

// workspace (bf16 elem offsets): transposed bf16 weights Bt[n][k]
#define O01 0         // c01wT [64][192]
#define O02 12288     // c02wT [64][192]
#define O11 24576     // c11wT [320][192]
#define O12 86016     // c12wT [320][1024]  (k<960: conv taps; k>=960: c1_p 1x1)
#define OD  413696    // dwT   [1280][320]
#define OP  823296    // pwT   [16][1280]   (rows 12..15 zero)
#define NWS 843776    // weight elems
#define OGM 843776    // Gm fp32 [12][12] (288 bf16 elems)
#define OF2 844064    // F2 fp32 [12]     (24 elems)

// LDS byte offsets (59248 total => 2 blocks/CU)
#define LA  0         // A: h0 raw -> h_b0 raw (T1)       [76][R64P] 10944
#define LB  10944     // Bf: gelu chain                   [76][R64P] 10944
#define LC  10944     // C (TB1) OVERLAYS Bf post-L3      [68][R320P] 44608 -> 55552
#define LXI 55552     // x_interp fp32 [64][12]  3072
#define LGM 58624     // fc_w@fcr_w    [12][12]  576
#define LF2 59200     // fused bias    [12]      48
#define LSZ 59248
// pass-2 aliases (A and C dead after L4):
#define LRR 0         // enc-out [64][R320P] bf16 = 41984
#define LZB 41984     // per-wave z chunk [16][R64P] bf16 = 2304 each, 4 waves

__device__ __forceinline__ float bf2f(const __hip_bfloat16 v) { return __bfloat162float(v); }
__device__ __forceinline__ __hip_bfloat16 f2bf(float f)       { return __float2bfloat16(f); }
__device__ __forceinline__ float geluf(float x) {
    return 0.5f * x * (1.0f + erff(x * 0.7071067811865475f));
}
__device__ __forceinline__ bf16x8 ldb8(const void* p) { return *(const bf16x8*)p; }

// ---- weight prep: fp32 -> bf16 transposed + Gm/F2, every launch ------------
extern "C" __global__ void __launch_bounds__(256) prep_w(
    const float* __restrict__ c01w, const float* __restrict__ c02w,
    const float* __restrict__ c11w, const float* __restrict__ c12w,
    const float* __restrict__ c1pw, const float* __restrict__ dw,
    const float* __restrict__ pw,
    const float* __restrict__ fcw,  const float* __restrict__ fcb,
    const float* __restrict__ fcrw, const float* __restrict__ fcrb,
    __hip_bfloat16* __restrict__ ws)
{
    for (size_t i = (size_t)blockIdx.x * 256 + threadIdx.x; i < NWS;
         i += (size_t)gridDim.x * 256) {
        float v;
        if (i < O02)      { int q = (int)i;        int n = q / 192, r = q % 192;
                            v = c01w[(n * 64 + (r & 63)) * 3 + (r >> 6)]; }
        else if (i < O11) { int q = (int)(i - O02); int n = q / 192, r = q % 192;
                            v = c02w[(n * 64 + (r & 63)) * 3 + (r >> 6)]; }
        else if (i < O12) { int q = (int)(i - O11); int n = q / 192, r = q % 192;
                            v = c11w[(n * 64 + (r & 63)) * 3 + (r >> 6)]; }
        else if (i < OD)  { int q = (int)(i - O12); int n = q >> 10, k = q & 1023;
                            v = (k < 960) ? c12w[(n * 320 + (k % 320)) * 3 + (k / 320)]
                                          : c1pw[n * 64 + (k - 960)]; }
        else if (i < OP)  { int q = (int)(i - OD);  int h = q / 320, c = q % 320;
                            v = dw[c * 1280 + h]; }
        else              { int q = (int)(i - OP);  int j = q / 1280, h = q % 1280;
                            v = (j < 12) ? pw[h * 12 + j] : 0.f; }
        ws[i] = f2bf(v);
    }
    if (blockIdx.x == 0) {
        float* gm = (float*)(ws + OGM);
        float* f2 = (float*)(ws + OF2);
        for (int o = threadIdx.x; o < 144; o += 256) {
            int j = o / 12, j2 = o - j * 12;
            float s = 0.f;
            for (int c = 0; c < C1; c++) s += fcw[j * C1 + c] * fcrw[c * 12 + j2];
            gm[o] = s;
        }
        if (threadIdx.x < 12) {
            float s = fcrb[threadIdx.x];
            for (int c = 0; c < C1; c++) s += fcb[c] * fcrw[c * 12 + threadIdx.x];
            f2[threadIdx.x] = s;
        }
    }
}

extern "C" __global__ void __launch_bounds__(256, 2) fused_main(
    const float* __restrict__ x1,  const float* __restrict__ X1,
    const float* __restrict__ X2,
    const float* __restrict__ w_in, const float* __restrict__ b_in,
    const float* __restrict__ c01b, const float* __restrict__ c02b,
    const float* __restrict__ c1pb, const float* __restrict__ c11b,
    const float* __restrict__ c12b,
    const float* __restrict__ db,   const float* __restrict__ pb,
    const __hip_bfloat16* __restrict__ ws,
    float* __restrict__ out)
{
    __shared__ __align__(16) unsigned char smem[LSZ];
    __hip_bfloat16* A  = (__hip_bfloat16*)(smem + LA);   // h0 -> T1
    __hip_bfloat16* Bf = (__hip_bfloat16*)(smem + LB);   // G0 -> T0 -> GH
    __hip_bfloat16* C  = (__hip_bfloat16*)(smem + LC);   // TB1 (rows p-4), overlays Bf
    float* XI = (float*)(smem + LXI);
    float* Gm = (float*)(smem + LGM);
    float* F2 = (float*)(smem + LF2);
    __hip_bfloat16* Rr = (__hip_bfloat16*)(smem + LRR);

    const int tid  = threadIdx.x;
    const int wv   = tid >> 6;
    const int lane = tid & 63;
    const int lm   = lane & 15;        // MFMA: A row / B col / D col
    const int lq   = lane >> 4;        // MFMA: k-octet / D row-quad
    const int bid  = blockIdx.x;
    const int pass = bid % 3;          // interleave heavy pass-2 blocks
    const int rem  = bid / 3;
    const int b    = rem >> 3;
    const int t0   = (rem & (NTILE - 1)) * TT;
    const float* xin = (pass == 0) ? X1 : (pass == 1) ? X2 : x1;

    const f32x4 Z4 = {0.f, 0.f, 0.f, 0.f};

    // ---- pass-2 prep: load Gm/F2 from ws, XI = ih_proj_b -------------------
    if (pass == 2) {
        const float* gmw = (const float*)(ws + OGM);
        const float* f2w = (const float*)(ws + OF2);
        for (int o = tid; o < 144; o += 256) Gm[o] = gmw[o];
        if (tid < 12) F2[tid] = f2w[tid];
        for (int o = tid; o < TT * 12; o += 256) XI[o] = pb[o % 12];
    }

    // ---- L0: x@w_in + b_in, rows [0,76) ------------------------------------
    for (int o = tid; o < PP * C0; o += 256) {
        int p = o >> 6, c = o & 63;
        int t = t0 + p - HALO;
        float acc = 0.f;
        if (t >= 0 && t < TSEQ) {
            acc = b_in[c];
            const float4* xr4 = (const float4*)(xin + ((size_t)b * TSEQ + t) * DIN);
            float4 v0 = xr4[0], v1 = xr4[1], v2 = xr4[2];
            const float xv[12] = {v0.x, v0.y, v0.z, v0.w, v1.x, v1.y,
                                  v1.z, v1.w, v2.x, v2.y, v2.z, v2.w};
            #pragma unroll
            for (int i = 0; i < DIN; i++) acc += xv[i] * w_in[i * C0 + c];
        }
        A [p * R64P + c] = f2bf(acc);
        Bf[p * R64P + c] = f2bf(geluf(acc));
    }
    __syncthreads();

    // ---- L1: conv0_1 64->64 k3 d1 on gelu(h0)=Bf, out rows [1,75) ----------
    // clamp p<=75; garbage A-rows (clamped) map to D rows >= 74 (masked).
    {
        const int oc = wv * 16 + lm;
        f32x4 acc[5] = {Z4, Z4, Z4, Z4, Z4};
        #pragma unroll
        for (int ks = 0; ks < 6; ks++) {
            int tap = ks >> 1, ci = ((ks & 1) << 5) + (lq << 3);
            bf16x8 bf = ldb8(ws + O01 + oc * 192 + ks * 32 + (lq << 3));
            #pragma unroll
            for (int mt = 0; mt < 5; mt++) {
                int p = 1 + mt * 16 + lm + tap - 1; p = p > 75 ? 75 : p;
                acc[mt] = MFMA16(ldb8(Bf + p * R64P + ci), bf, acc[mt]);
            }
        }
        __syncthreads();   // all waves done reading G0 before in-place write
        float bias = c01b[oc];
        #pragma unroll
        for (int mt = 0; mt < 5; mt++)
            #pragma unroll
            for (int r = 0; r < 4; r++) {
                int m = mt * 16 + lq * 4 + r;
                if (m < 74) {
                    int p = 1 + m, t = t0 + p - HALO;
                    Bf[p * R64P + oc] =
                        f2bf((t >= 0 && t < TSEQ) ? geluf(acc[mt][r] + bias) : 0.f);
                }
            }
    }
    __syncthreads();

    // ---- L2: conv0_2 on T0=Bf + residual h0=A, out rows [2,74) -------------
    // stale rows {0? no: p>=1} / {74,75} feed D rows >= 72 (masked).
    {
        const int oc = wv * 16 + lm;
        f32x4 acc[5] = {Z4, Z4, Z4, Z4, Z4};
        #pragma unroll
        for (int ks = 0; ks < 6; ks++) {
            int tap = ks >> 1, ci = ((ks & 1) << 5) + (lq << 3);
            bf16x8 bf = ldb8(ws + O02 + oc * 192 + ks * 32 + (lq << 3));
            #pragma unroll
            for (int mt = 0; mt < 5; mt++) {
                int p = 2 + mt * 16 + lm + tap - 1; p = p > 75 ? 75 : p;
                acc[mt] = MFMA16(ldb8(Bf + p * R64P + ci), bf, acc[mt]);
            }
        }
        float resv[5][4];
        #pragma unroll
        for (int mt = 0; mt < 5; mt++)
            #pragma unroll
            for (int r = 0; r < 4; r++) {
                int m = mt * 16 + lq * 4 + r;
                resv[mt][r] = (m < 72) ? bf2f(A[(2 + m) * R64P + oc]) : 0.f;
            }
        __syncthreads();   // reads of Bf and A complete
        float bias = c02b[oc];
        #pragma unroll
        for (int mt = 0; mt < 5; mt++)
            #pragma unroll
            for (int r = 0; r < 4; r++) {
                int m = mt * 16 + lq * 4 + r;
                if (m < 72) {
                    int p = 2 + m, t = t0 + p - HALO;
                    bool v = (t >= 0 && t < TSEQ);
                    float hb = acc[mt][r] + bias + resv[mt][r];
                    A [p * R64P + oc] = f2bf(v ? hb : 0.f);          // T1 raw
                    Bf[p * R64P + oc] = f2bf(v ? geluf(hb) : 0.f);   // GH
                }
            }
    }
    __syncthreads();

    // ---- L3: c1_1 64->320 k3 d2 on GH=Bf, out rows [4,72) -> C[m<68] -------
    // pipelined: prefetch ks+1 (5 LDS A + 5 global B) while MFMAing ks.
    // stale rows {74,75}/clamped feed D rows >= 68 (masked).
    {
        f32x4 acc[5][5];
        #pragma unroll
        for (int mt = 0; mt < 5; mt++)
            #pragma unroll
            for (int nt = 0; nt < 5; nt++) acc[mt][nt] = Z4;
        bf16x8 aa[5], ba[5], ab[5], bb[5];
        auto ld3 = [&](int ks, bf16x8 (&a)[5], bf16x8 (&bw)[5]) {
            int tap = ks >> 1, ci = ((ks & 1) << 5) + (lq << 3);
            #pragma unroll
            for (int mt = 0; mt < 5; mt++) {
                int p = 4 + mt * 16 + lm + 2 * (tap - 1); p = p > 75 ? 75 : p;
                a[mt] = ldb8(Bf + p * R64P + ci);
            }
            #pragma unroll
            for (int nt = 0; nt < 5; nt++)
                bw[nt] = ldb8(ws + O11 + (wv * 80 + nt * 16 + lm) * 192
                              + ks * 32 + (lq << 3));
        };
        ld3(0, aa, ba);
        #pragma unroll
        for (int ks = 0; ks < 6; ks += 2) {
            ld3(ks + 1, ab, bb);
            #pragma unroll
            for (int nt = 0; nt < 5; nt++)
                #pragma unroll
                for (int mt = 0; mt < 5; mt++)
                    acc[mt][nt] = MFMA16(aa[mt], ba[nt], acc[mt][nt]);
            if (ks + 2 < 6) ld3(ks + 2, aa, ba);
            #pragma unroll
            for (int nt = 0; nt < 5; nt++)
                #pragma unroll
                for (int mt = 0; mt < 5; mt++)
                    acc[mt][nt] = MFMA16(ab[mt], bb[nt], acc[mt][nt]);
        }
        __syncthreads();   // all waves done reading Bf before C overlays it
        #pragma unroll
        for (int nt = 0; nt < 5; nt++) {
            int oc = wv * 80 + nt * 16 + lm;
            float bias = c11b[oc];
            #pragma unroll
            for (int mt = 0; mt < 5; mt++)
                #pragma unroll
                for (int r = 0; r < 4; r++) {
                    int m = mt * 16 + lq * 4 + r;
                    if (m < 68) {
                        int t = t0 + 4 + m - HALO;
                        C[m * R320P + oc] =
                            f2bf((t >= 0 && t < TSEQ) ? geluf(acc[mt][nt][r] + bias) : 0.f);
                    }
                }
        }
    }
    __syncthreads();

    // ---- L4: c1_2 320->320 k3 d2 (K=960) + c1_p 1x1 on T1=A (K=64) ---------
    // out rows [6,70) == 64 exactly (no mask). C rows [0,68) cover all taps.
    {
        f32x4 acc[4][5];
        #pragma unroll
        for (int mt = 0; mt < 4; mt++)
            #pragma unroll
            for (int nt = 0; nt < 5; nt++) acc[mt][nt] = Z4;
        bf16x8 aa[4], ba[5], ab[4], bb[5];
        auto ld4 = [&](int ks, bf16x8 (&a)[4], bf16x8 (&bw)[5]) {
            if (ks < 30) {
                int tap = (ks >= 20) ? 2 : (ks >= 10 ? 1 : 0);
                int ci = (ks - tap * 10) * 32 + (lq << 3);
                #pragma unroll
                for (int mt = 0; mt < 4; mt++)
                    a[mt] = ldb8(C + (2 + mt * 16 + lm + 2 * (tap - 1)) * R320P + ci);
            } else {
                int ci = ((ks - 30) << 5) + (lq << 3);
                #pragma unroll
                for (int mt = 0; mt < 4; mt++)
                    a[mt] = ldb8(A + (6 + mt * 16 + lm) * R64P + ci);
            }
            #pragma unroll
            for (int nt = 0; nt < 5; nt++)
                bw[nt] = ldb8(ws + O12 + (wv * 80 + nt * 16 + lm) * 1024
                              + ks * 32 + (lq << 3));
        };
        ld4(0, aa, ba);
        for (int ks = 0; ks < 32; ks += 2) {
            ld4(ks + 1, ab, bb);
            #pragma unroll
            for (int nt = 0; nt < 5; nt++)
                #pragma unroll
                for (int mt = 0; mt < 4; mt++)
                    acc[mt][nt] = MFMA16(aa[mt], ba[nt], acc[mt][nt]);
            if (ks + 2 < 32) ld4(ks + 2, aa, ba);
            #pragma unroll
            for (int nt = 0; nt < 5; nt++)
                #pragma unroll
                for (int mt = 0; mt < 4; mt++)
                    acc[mt][nt] = MFMA16(ab[mt], bb[nt], acc[mt][nt]);
        }
        if (pass < 2) {
            #pragma unroll
            for (int nt = 0; nt < 5; nt++) {
                int oc = wv * 80 + nt * 16 + lm;
                float bias = c12b[oc] + c1pb[oc];
                const size_t obase = (pass == 1) ? S1 : (size_t)0;
                #pragma unroll
                for (int mt = 0; mt < 4; mt++)
                    #pragma unroll
                    for (int r = 0; r < 4; r++) {
                        int m = mt * 16 + lq * 4 + r;
                        out[obase + ((size_t)b * TSEQ + t0 + m) * C1 + oc] =
                            acc[mt][nt][r] + bias;
                    }
            }
        } else {
            __syncthreads();   // all waves done reading C,A -> safe to alias Rr
            #pragma unroll
            for (int nt = 0; nt < 5; nt++) {
                int oc = wv * 80 + nt * 16 + lm;
                float bias = c12b[oc] + c1pb[oc];
                #pragma unroll
                for (int mt = 0; mt < 4; mt++)
                    #pragma unroll
                    for (int r = 0; r < 4; r++) {
                        int m = mt * 16 + lq * 4 + r;
                        Rr[m * R320P + oc] = f2bf(acc[mt][nt][r] + bias);
                    }
            }
            __syncthreads();   // Rr complete (cross-wave K in dense stage)
        }
    }

    // ---- pass-2: dense 320->1280, relu, @pw (MFMA), @Gm, outputs -----------
    if (pass == 2) {
        __hip_bfloat16* zb = (__hip_bfloat16*)(smem + LZB) + wv * (16 * R64P);
        f32x4 xacc[4] = {Z4, Z4, Z4, Z4};
        for (int cn = 0; cn < 5; cn++) {
            const int h0 = wv * 320 + cn * 64;
            f32x4 dacc[4][4];
            #pragma unroll
            for (int mt = 0; mt < 4; mt++)
                #pragma unroll
                for (int nt = 0; nt < 4; nt++) dacc[mt][nt] = Z4;
            bf16x8 aa[4], ba[4], ab[4], bb[4];
            auto ldd = [&](int ks, bf16x8 (&a)[4], bf16x8 (&bw)[4]) {
                int ci = ks * 32 + (lq << 3);
                #pragma unroll
                for (int mt = 0; mt < 4; mt++)
                    a[mt] = ldb8(Rr + (mt * 16 + lm) * R320P + ci);
                #pragma unroll
                for (int nt = 0; nt < 4; nt++)
                    bw[nt] = ldb8(ws + OD + (h0 + nt * 16 + lm) * 320 + ci);
            };
            ldd(0, aa, ba);
            #pragma unroll
            for (int ks = 0; ks < 10; ks += 2) {
                ldd(ks + 1, ab, bb);
                #pragma unroll
                for (int nt = 0; nt < 4; nt++)
                    #pragma unroll
                    for (int mt = 0; mt < 4; mt++)
                        dacc[mt][nt] = MFMA16(aa[mt], ba[nt], dacc[mt][nt]);
                if (ks + 2 < 10) ldd(ks + 2, aa, ba);
                #pragma unroll
                for (int nt = 0; nt < 4; nt++)
                    #pragma unroll
                    for (int mt = 0; mt < 4; mt++)
                        dacc[mt][nt] = MFMA16(ab[mt], bb[nt], dacc[mt][nt]);
            }
            // per-mt: relu -> zb (wave-private, DS in-order) -> proj MFMA
            #pragma unroll
            for (int mt = 0; mt < 4; mt++) {
                #pragma unroll
                for (int nt = 0; nt < 4; nt++) {
                    int h = h0 + nt * 16 + lm;
                    float dbv = db[h];
                    #pragma unroll
                    for (int r = 0; r < 4; r++)
                        zb[(lq * 4 + r) * R64P + nt * 16 + lm] =
                            f2bf(fmaxf(dacc[mt][nt][r] + dbv, 0.f));
                }
                #pragma unroll
                for (int k2 = 0; k2 < 2; k2++) {
                    int hl = k2 * 32 + (lq << 3);
                    bf16x8 bf = ldb8(ws + OP + lm * 1280 + h0 + hl);
                    xacc[mt] = MFMA16(ldb8(zb + lm * R64P + hl), bf, xacc[mt]);
                }
            }
        }
        if (lm < 12) {
            #pragma unroll
            for (int mt = 0; mt < 4; mt++)
                #pragma unroll
                for (int r = 0; r < 4; r++)
                    atomicAdd(&XI[(mt * 16 + lq * 4 + r) * 12 + lm], xacc[mt][r]);
        }
        __syncthreads();
        for (int o = tid; o < TT * 12; o += 256) {
            int p = o / 12, j2 = o - p * 12;
            float val = F2[j2];
            #pragma unroll
            for (int j = 0; j < 12; j++) val += XI[p * 12 + j] * Gm[j * 12 + j2];
            size_t idx = ((size_t)b * TSEQ + t0 + p) * DIN + j2;
            out[2 * S1 + idx]      = val;   // outputs1
            out[2 * S1 + S2 + idx] = val;   // outputs2 (ref uses y_t1 for both)
        }
    }
}

// ---- masks + passthrough: m1, m2, x1, x2 -----------------------------------
extern "C" __global__ void __launch_bounds__(256) tail_kernel(
    const float* __restrict__ x1, const float* __restrict__ x2,
    float* __restrict__ out)
{
    size_t i = (size_t)blockIdx.x * 256 + threadIdx.x;
    if (i >= S2) return;
    float a = x1[i], c = x2[i];
    const size_t base = 2 * S1 + 2 * S2;
    out[base + i]          = (a != 0.f) ? 1.f : 0.f;
    out[base + S2 + i]     = (c != 0.f) ? 1.f : 0.f;
    out[base + 2 * S2 + i] = a;
    out[base + 3 * S2 + i] = c;
}

extern "C" void kernel_launch(void* const* d_in, const int* in_sizes, int n_in,
                              void* d_out, int out_size, void* d_ws, size_t ws_size,
                              hipStream_t stream)
{
    (void)in_sizes; (void)n_in; (void)ws_size; (void)out_size;
    const float* x1   = (const float*)d_in[0];
    const float* x2   = (const float*)d_in[1];
    const float* X1   = (const float*)d_in[2];
    const float* X2   = (const float*)d_in[3];
    const float* w_in = (const float*)d_in[5];
    const float* b_in = (const float*)d_in[6];
    const float* c01w = (const float*)d_in[7];
    const float* c01b = (const float*)d_in[8];
    const float* c02w = (const float*)d_in[9];
    const float* c02b = (const float*)d_in[10];
    const float* c1pw = (const float*)d_in[11];
    const float* c1pb = (const float*)d_in[12];
    const float* c11w = (const float*)d_in[13];
    const float* c11b = (const float*)d_in[14];
    const float* c12w = (const float*)d_in[15];
    const float* c12b = (const float*)d_in[16];
    const float* dwp  = (const float*)d_in[17];
    const float* dbp  = (const float*)d_in[18];
    const float* pwp  = (const float*)d_in[19];
    const float* pbp  = (const float*)d_in[20];
    const float* fcw  = (const float*)d_in[21];
    const float* fcb  = (const float*)d_in[22];
    const float* fcrw = (const float*)d_in[29];
    const float* fcrb = (const float*)d_in[30];
    float* out = (float*)d_out;
    __hip_bfloat16* ws = (__hip_bfloat16*)d_ws;

    prep_w<<<824, 256, 0, stream>>>(c01w, c02w, c11w, c12w, c1pw, dwp, pwp,
                                    fcw, fcb, fcrw, fcrb, ws);

    fused_main<<<3 * BB * NTILE, 256, 0, stream>>>(
        x1, X1, X2, w_in, b_in, c01b, c02b, c1pb, c11b, c12b,
        dbp, pbp, ws, out);

    tail_kernel<<<(int)((S2 + 255) / 256), 256, 0, stream>>>(x1, x2, out);
}